// Round 2
// baseline (303.758 us; speedup 1.0000x reference)
//
#include <hip/hip_runtime.h>

// RouterAttention on gfx950. B=4 L=S=4096 D=512 H=8 E=R=64.
// Dtype self-detected (bf16 vs f32 inputs) via sniff_k; pipeline runs bf16 MFMA.

#define DEV __device__ __forceinline__

constexpr int Bn = 4, Ln = 4096, Dn = 512, Hn = 8, En = 64, Rn = 64;
constexpr int Sn = 4096;
constexpr float SCALE = 0.125f;                 // 1/sqrt(E)
constexpr float L2B_OVER_K = 13.287712379549449f / 32.0f; // log2(10000)/32

typedef __bf16 bf16x8 __attribute__((ext_vector_type(8)));
typedef float floatx4 __attribute__((ext_vector_type(4)));

DEV float bf2f(ushort u) { return __uint_as_float(((unsigned)u) << 16); }
DEV ushort f2bf(float f) {
    unsigned u = __float_as_uint(f);
    u += 0x7fffu + ((u >> 16) & 1u);            // RNE
    return (ushort)(u >> 16);
}
DEV bf16x8 ldsfrag(const ushort* p) { return *reinterpret_cast<const bf16x8*>(p); }
#define MFMA(a, b, c) __builtin_amdgcn_mfma_f32_16x16x32_bf16(a, b, c, 0, 0, 0)

DEV float wave_max(float v) {
    #pragma unroll
    for (int off = 1; off < 64; off <<= 1) v = fmaxf(v, __shfl_xor(v, off));
    return v;
}
DEV float wave_sum(float v) {
    #pragma unroll
    for (int off = 1; off < 64; off <<= 1) v += __shfl_xor(v, off);
    return v;
}
DEV int wave_sum_i(int v) {
    #pragma unroll
    for (int off = 1; off < 64; off <<= 1) v += __shfl_xor(v, off);
    return v;
}

// ---- dtype sniffer: flag=1 if x looks like f32, 0 if bf16-packed ----
// bits 14:7 of each u32 = low halfword's bf16 exponent. N(0,1) bf16 -> ~always
// in [100,140]; f32 mantissa bits -> ~16% in range.
__global__ __launch_bounds__(256) void sniff_k(const uint* __restrict__ x, int* __restrict__ flag) {
    int t = threadIdx.x, cnt = 0;
    #pragma unroll
    for (int i = 0; i < 16; ++i) {
        uint u = x[t * 16 + i];
        uint e = (u >> 7) & 0xFF;
        cnt += (e >= 100 && e <= 140) ? 1 : 0;
    }
    cnt = wave_sum_i(cnt);
    __shared__ int red[4];
    int w = t >> 6, l = t & 63;
    if (l == 0) red[w] = cnt;
    __syncthreads();
    if (t == 0) flag[0] = ((red[0] + red[1] + red[2] + red[3]) < 2048) ? 1 : 0;
}

// ---- canonicalize all 10 inputs into contiguous bf16 region ----
constexpr size_t SEG1 = 8388608, SEG2 = 8650752, SEG3 = 8651264, SEG4 = 8913408,
                 SEG5 = 8913920, SEG6 = 9176064, SEG7 = 9176576, SEG8 = 9438720,
                 SEG9 = 9439232, SEGT = 9472000;
__global__ __launch_bounds__(256)
void canon_k(const void* p0, const void* p1, const void* p2, const void* p3,
             const void* p4, const void* p5, const void* p6, const void* p7,
             const void* p8, const void* p9, const int* __restrict__ flag,
             ushort* __restrict__ dst) {
    const int f = *flag;
    size_t i0 = (size_t)blockIdx.x * 1024 + threadIdx.x;
    #pragma unroll
    for (int r = 0; r < 4; ++r) {
        size_t i = i0 + (size_t)r * 256;
        if (i >= SEGT) return;
        const void* sp; size_t off;
        if      (i < SEG1) { sp = p0; off = i; }
        else if (i < SEG2) { sp = p1; off = i - SEG1; }
        else if (i < SEG3) { sp = p2; off = i - SEG2; }
        else if (i < SEG4) { sp = p3; off = i - SEG3; }
        else if (i < SEG5) { sp = p4; off = i - SEG4; }
        else if (i < SEG6) { sp = p5; off = i - SEG5; }
        else if (i < SEG7) { sp = p6; off = i - SEG6; }
        else if (i < SEG8) { sp = p7; off = i - SEG7; }
        else if (i < SEG9) { sp = p8; off = i - SEG8; }
        else               { sp = p9; off = i - SEG9; }
        dst[i] = f ? f2bf(((const float*)sp)[off]) : ((const ushort*)sp)[off];
    }
}

// ---- rope table: tab[p*32+j] = (cos, sin) of (S-1-p)*theta_j ----
__global__ __launch_bounds__(256) void rope_tab_k(float2* __restrict__ tab) {
    int idx = blockIdx.x * 256 + threadIdx.x;   // 131072 entries
    int p = idx >> 5, j = idx & 31;
    float theta = exp2f(-(float)j * L2B_OVER_K);
    float ang = (float)(Sn - 1 - p) * theta;
    float s, c;
    sincosf(ang, &s, &c);
    tab[idx] = make_float2(c, s);
}

// ---- 512x512 bf16 transpose: Wt[dout][din] = W[din][dout] ----
__global__ __launch_bounds__(256) void transpose_k(const ushort* __restrict__ W, ushort* __restrict__ Wt) {
    __shared__ ushort t[64][65];
    int tid = threadIdx.x;
    int c = tid & 63, r0 = (tid >> 6) * 16;
    int bx = blockIdx.x * 64, by = blockIdx.y * 64;
    #pragma unroll
    for (int i = 0; i < 16; ++i) t[r0 + i][c] = W[(size_t)(by + r0 + i) * Dn + bx + c];
    __syncthreads();
    #pragma unroll
    for (int i = 0; i < 16; ++i) Wt[(size_t)(bx + r0 + i) * Dn + by + c] = t[c][r0 + i];
}

// ---- projection GEMM: Out[n][d] = act(sum_k X[n][k]*Wt[d][k] + bias[d]) ----
__global__ __launch_bounds__(256)
void gemm_proj_k(const ushort* __restrict__ X, const ushort* __restrict__ Wt,
                 const ushort* __restrict__ bias, ushort* __restrict__ Out, int act) {
    __shared__ ushort As[64][40];
    __shared__ ushort Bs[64][40];
    const int tid = threadIdx.x;
    const int d0 = blockIdx.x * 64;
    const int n0 = blockIdx.y * 64;
    const int w = tid >> 6, l = tid & 63;
    const int mt = (w >> 1) * 32, nt = (w & 1) * 32;
    const int lr = l & 15, lq = l >> 4;
    const int sm = tid >> 2, sg = (tid & 3) * 8;
    floatx4 acc[2][2] = {};
    for (int kc = 0; kc < Dn; kc += 32) {
        __syncthreads();
        *(uint4*)&As[sm][sg] = *(const uint4*)&X[(size_t)(n0 + sm) * Dn + kc + sg];
        *(uint4*)&Bs[sm][sg] = *(const uint4*)&Wt[(size_t)(d0 + sm) * Dn + kc + sg];
        __syncthreads();
        bf16x8 a0 = ldsfrag(&As[mt + lr][lq * 8]);
        bf16x8 a1 = ldsfrag(&As[mt + 16 + lr][lq * 8]);
        bf16x8 b0 = ldsfrag(&Bs[nt + lr][lq * 8]);
        bf16x8 b1 = ldsfrag(&Bs[nt + 16 + lr][lq * 8]);
        acc[0][0] = MFMA(a0, b0, acc[0][0]);
        acc[0][1] = MFMA(a0, b1, acc[0][1]);
        acc[1][0] = MFMA(a1, b0, acc[1][0]);
        acc[1][1] = MFMA(a1, b1, acc[1][1]);
    }
    #pragma unroll
    for (int mi = 0; mi < 2; ++mi)
        #pragma unroll
        for (int ni = 0; ni < 2; ++ni) {
            int col = d0 + nt + ni * 16 + lr;
            float bb = bf2f(bias[col]);
            #pragma unroll
            for (int ri = 0; ri < 4; ++ri) {
                int row = n0 + mt + mi * 16 + lq * 4 + ri;
                float v = acc[mi][ni][ri] + bb;
                if (act) v = v / (1.0f + __expf(-v));   // silu
                Out[(size_t)row * Dn + col] = f2bf(v);
            }
        }
}

// ---- router scores: P[bh][r][s] = sum_e r[h,r,e]*k[b,s,h,e] ----
__global__ __launch_bounds__(256)
void router_scores_k(const ushort* __restrict__ RP, const ushort* __restrict__ Kb, float* __restrict__ P) {
    __shared__ ushort As[64][72];
    __shared__ ushort Bs[64][72];
    const int tid = threadIdx.x;
    const int bh = blockIdx.y, b = bh >> 3, h = bh & 7;
    const int s0 = blockIdx.x * 64;
    #pragma unroll
    for (int q2 = 0; q2 < 2; ++q2) {
        int lin = q2 * 256 + tid, row = lin >> 3, g = (lin & 7) * 8;
        *(uint4*)&As[row][g] = *(const uint4*)&RP[(size_t)row * Dn + h * En + g];
        *(uint4*)&Bs[row][g] = *(const uint4*)&Kb[(size_t)(b * Ln + s0 + row) * Dn + h * En + g];
    }
    __syncthreads();
    const int w = tid >> 6, l = tid & 63;
    const int mt = (w >> 1) * 32, nt = (w & 1) * 32, lr = l & 15, lq = l >> 4;
    floatx4 acc[2][2] = {};
    #pragma unroll
    for (int ks = 0; ks < 64; ks += 32) {
        bf16x8 a0 = ldsfrag(&As[mt + lr][ks + lq * 8]);
        bf16x8 a1 = ldsfrag(&As[mt + 16 + lr][ks + lq * 8]);
        bf16x8 b0 = ldsfrag(&Bs[nt + lr][ks + lq * 8]);
        bf16x8 b1 = ldsfrag(&Bs[nt + 16 + lr][ks + lq * 8]);
        acc[0][0] = MFMA(a0, b0, acc[0][0]);
        acc[0][1] = MFMA(a0, b1, acc[0][1]);
        acc[1][0] = MFMA(a1, b0, acc[1][0]);
        acc[1][1] = MFMA(a1, b1, acc[1][1]);
    }
    #pragma unroll
    for (int mi = 0; mi < 2; ++mi)
        #pragma unroll
        for (int ni = 0; ni < 2; ++ni)
            #pragma unroll
            for (int ri = 0; ri < 4; ++ri) {
                int r = mt + mi * 16 + lq * 4 + ri;
                int s = s0 + nt + ni * 16 + lr;
                P[((size_t)bh * Rn + r) * Sn + s] = acc[mi][ni][ri];
            }
}

// ---- row softmax over S, in place ----
__global__ __launch_bounds__(256)
void softmax_rows_k(float* __restrict__ P) {
    size_t base = (size_t)blockIdx.x * Sn;
    int tid = threadIdx.x, w = tid >> 6, l = tid & 63;
    float v[16];
    float m = -1e30f;
    #pragma unroll
    for (int i = 0; i < 16; ++i) { v[i] = P[base + i * 256 + tid]; m = fmaxf(m, v[i]); }
    __shared__ float red[4], red2[4];
    m = wave_max(m);
    if (l == 0) red[w] = m;
    __syncthreads();
    m = fmaxf(fmaxf(red[0], red[1]), fmaxf(red[2], red[3]));
    float s = 0.f;
    #pragma unroll
    for (int i = 0; i < 16; ++i) { v[i] = __expf(SCALE * (v[i] - m)); s += v[i]; }
    s = wave_sum(s);
    if (l == 0) red2[w] = s;
    __syncthreads();
    float inv = 1.0f / (red2[0] + red2[1] + red2[2] + red2[3]);
    #pragma unroll
    for (int i = 0; i < 16; ++i) P[base + i * 256 + tid] = v[i] * inv;
}

// ---- rV[bh][r][e] += sum_s rope(P)[r][s] * v[s][e] ----
__global__ __launch_bounds__(256)
void router_v_k(const float* __restrict__ P, const ushort* __restrict__ X,
                const float2* __restrict__ tab, float* __restrict__ rV) {
    __shared__ ushort As[64][72];
    __shared__ ushort Bs[64][72];
    const int tid = threadIdx.x;
    const int bh = blockIdx.y, b = bh >> 3, h = bh & 7;
    const int w = tid >> 6, l = tid & 63;
    const int mt = (w >> 1) * 32, nt = (w & 1) * 32, lr = l & 15, lq = l >> 4;
    floatx4 acc[2][2] = {};
    for (int t4 = 0; t4 < 4; ++t4) {
        const int sb = blockIdx.x * 256 + t4 * 64;
        __syncthreads();
        #pragma unroll
        for (int i = 0; i < 8; ++i) {
            int lin = i * 256 + tid;
            int j = lin >> 6, sl = lin & 63;
            int sg2 = sb + sl;
            float pe = P[((size_t)bh * Rn + 2 * j) * Sn + sg2];
            float po = P[((size_t)bh * Rn + 2 * j + 1) * Sn + sg2];
            float2 cs = tab[sg2 * 32 + j];
            As[2 * j][sl]     = f2bf(pe * cs.x - po * cs.y);
            As[2 * j + 1][sl] = f2bf(pe * cs.y + po * cs.x);
        }
        #pragma unroll
        for (int i = 0; i < 16; ++i) {
            int lin = i * 256 + tid;
            int sl = lin >> 6, e = lin & 63;
            Bs[e][sl] = X[(size_t)(b * Ln + sb + sl) * Dn + h * En + e];
        }
        __syncthreads();
        #pragma unroll
        for (int ks = 0; ks < 64; ks += 32) {
            bf16x8 a0 = ldsfrag(&As[mt + lr][ks + lq * 8]);
            bf16x8 a1 = ldsfrag(&As[mt + 16 + lr][ks + lq * 8]);
            bf16x8 b0 = ldsfrag(&Bs[nt + lr][ks + lq * 8]);
            bf16x8 b1 = ldsfrag(&Bs[nt + 16 + lr][ks + lq * 8]);
            acc[0][0] = MFMA(a0, b0, acc[0][0]);
            acc[0][1] = MFMA(a0, b1, acc[0][1]);
            acc[1][0] = MFMA(a1, b0, acc[1][0]);
            acc[1][1] = MFMA(a1, b1, acc[1][1]);
        }
    }
    #pragma unroll
    for (int mi = 0; mi < 2; ++mi)
        #pragma unroll
        for (int ni = 0; ni < 2; ++ni)
            #pragma unroll
            for (int ri = 0; ri < 4; ++ri) {
                int r = mt + mi * 16 + lq * 4 + ri;
                int e = nt + ni * 16 + lr;
                atomicAdd(&rV[((size_t)bh * Rn + r) * En + e], acc[mi][ni][ri]);
            }
}

// ---- fused query path: qs=q@r^T -> softmax(r) -> rope -> @rV -> (+skip)*z ----
__global__ __launch_bounds__(256)
void final_attn_k(const ushort* __restrict__ Q, const ushort* __restrict__ RP,
                  const float* __restrict__ rV, const float2* __restrict__ tab,
                  const ushort* __restrict__ Skip, const ushort* __restrict__ Zs,
                  const int* __restrict__ flagp, void* __restrict__ Outv) {
    __shared__ ushort Aq[64][72];
    __shared__ ushort Brp[64][72];
    __shared__ ushort Ap[64][72];
    __shared__ ushort BvT[64][72];
    __shared__ float qsc[64][65];
    const int f = *flagp;
    const int tid = threadIdx.x;
    const int h = blockIdx.y, b = blockIdx.z, bh = b * Hn + h;
    const int l0 = blockIdx.x * 64;
    const int w = tid >> 6, l = tid & 63;
    const int mt = (w >> 1) * 32, nt = (w & 1) * 32, lr = l & 15, lq = l >> 4;
    #pragma unroll
    for (int q2 = 0; q2 < 2; ++q2) {
        int lin = q2 * 256 + tid, row = lin >> 3, g = (lin & 7) * 8;
        *(uint4*)&Aq[row][g]  = *(const uint4*)&Q[(size_t)(b * Ln + l0 + row) * Dn + h * En + g];
        *(uint4*)&Brp[row][g] = *(const uint4*)&RP[(size_t)row * Dn + h * En + g];
    }
    #pragma unroll
    for (int i = 0; i < 16; ++i) {
        int lin = i * 256 + tid, r = lin >> 6, e = lin & 63;
        BvT[e][r] = f2bf(rV[((size_t)bh * Rn + r) * En + e]);
    }
    __syncthreads();
    {   // q_scores GEMM: m=token, n=r, k=e
        floatx4 acc[2][2] = {};
        #pragma unroll
        for (int ks = 0; ks < 64; ks += 32) {
            bf16x8 a0 = ldsfrag(&Aq[mt + lr][ks + lq * 8]);
            bf16x8 a1 = ldsfrag(&Aq[mt + 16 + lr][ks + lq * 8]);
            bf16x8 b0 = ldsfrag(&Brp[nt + lr][ks + lq * 8]);
            bf16x8 b1 = ldsfrag(&Brp[nt + 16 + lr][ks + lq * 8]);
            acc[0][0] = MFMA(a0, b0, acc[0][0]);
            acc[0][1] = MFMA(a0, b1, acc[0][1]);
            acc[1][0] = MFMA(a1, b0, acc[1][0]);
            acc[1][1] = MFMA(a1, b1, acc[1][1]);
        }
        #pragma unroll
        for (int mi = 0; mi < 2; ++mi)
            #pragma unroll
            for (int ni = 0; ni < 2; ++ni)
                #pragma unroll
                for (int ri = 0; ri < 4; ++ri)
                    qsc[mt + mi * 16 + lq * 4 + ri][nt + ni * 16 + lr] = acc[mi][ni][ri] * SCALE;
    }
    __syncthreads();
    #pragma unroll
    for (int ii = 0; ii < 16; ++ii) {
        int lt = ii * 4 + w;
        float sv = qsc[lt][l];
        float mx = wave_max(sv);
        float p = __expf(sv - mx);
        float sum = wave_sum(p);
        float A = p / sum;
        float Axp = __shfl_xor(A, 1);
        float2 cs = tab[(l0 + lt) * 32 + (l >> 1)];
        float Ar = (l & 1) ? (Axp * cs.y + A * cs.x) : (A * cs.x - Axp * cs.y);
        Ap[lt][l] = f2bf(Ar);
    }
    __syncthreads();
    {   // V GEMM: m=token, n=e, k=r; fused epilogue
        floatx4 acc[2][2] = {};
        #pragma unroll
        for (int ks = 0; ks < 64; ks += 32) {
            bf16x8 a0 = ldsfrag(&Ap[mt + lr][ks + lq * 8]);
            bf16x8 a1 = ldsfrag(&Ap[mt + 16 + lr][ks + lq * 8]);
            bf16x8 b0 = ldsfrag(&BvT[nt + lr][ks + lq * 8]);
            bf16x8 b1 = ldsfrag(&BvT[nt + 16 + lr][ks + lq * 8]);
            acc[0][0] = MFMA(a0, b0, acc[0][0]);
            acc[0][1] = MFMA(a0, b1, acc[0][1]);
            acc[1][0] = MFMA(a1, b0, acc[1][0]);
            acc[1][1] = MFMA(a1, b1, acc[1][1]);
        }
        #pragma unroll
        for (int mi = 0; mi < 2; ++mi)
            #pragma unroll
            for (int ni = 0; ni < 2; ++ni)
                #pragma unroll
                for (int ri = 0; ri < 4; ++ri) {
                    int row = mt + mi * 16 + lq * 4 + ri;
                    int e = nt + ni * 16 + lr;
                    size_t idx = (size_t)(b * Ln + l0 + row) * Dn + h * En + e;
                    float v = acc[mi][ni][ri];
                    float val = (v + bf2f(Skip[idx])) * bf2f(Zs[idx]);
                    if (f) ((float*)Outv)[idx] = val;
                    else   ((ushort*)Outv)[idx] = f2bf(val);
                }
    }
}

extern "C" void kernel_launch(void* const* d_in, const int* in_sizes, int n_in,
                              void* d_out, int out_size, void* d_ws, size_t ws_size,
                              hipStream_t stream) {
    // ws layout (bytes)
    const size_t OFF_Q     = 0;
    const size_t OFF_K     = 16777216;
    const size_t OFF_SK    = 2 * 16777216;
    const size_t OFF_Z     = 3 * 16777216;
    const size_t OFF_P     = 4 * 16777216;            // 32 MiB
    const size_t OFF_RV    = OFF_P + 33554432;        // 512 KiB
    const size_t OFF_TAB   = OFF_RV + 524288;         // 1 MiB
    const size_t OFF_WT    = OFF_TAB + 1048576;       // 2 MiB
    const size_t OFF_CANON = OFF_WT + 2097152;        // 18,944,000 B
    const size_t OFF_FLAG  = OFF_CANON + 18944000;
    const size_t NEED      = OFF_FLAG + 16;           // ~123.3 MB
    if (ws_size < NEED) return;                       // absmax 14.25 => ws too small

    char* ws = (char*)d_ws;
    ushort* q     = (ushort*)(ws + OFF_Q);
    ushort* k     = (ushort*)(ws + OFF_K);
    ushort* skip  = (ushort*)(ws + OFF_SK);
    ushort* z     = (ushort*)(ws + OFF_Z);
    float*  P     = (float*)(ws + OFF_P);
    float*  rV    = (float*)(ws + OFF_RV);
    float2* tab   = (float2*)(ws + OFF_TAB);
    ushort* Wt    = (ushort*)(ws + OFF_WT);
    ushort* canon = (ushort*)(ws + OFF_CANON);
    int*    flag  = (int*)(ws + OFF_FLAG);

    const ushort* Xc   = canon;
    const ushort* Wqc  = canon + SEG1;
    const ushort* bqc  = canon + SEG2;
    const ushort* Wkc  = canon + SEG3;
    const ushort* bkc  = canon + SEG4;
    const ushort* Wskc = canon + SEG5;
    const ushort* bskc = canon + SEG6;
    const ushort* Wzc  = canon + SEG7;
    const ushort* bzc  = canon + SEG8;
    const ushort* RPc  = canon + SEG9;

    sniff_k<<<1, 256, 0, stream>>>((const uint*)d_in[0], flag);
    canon_k<<<9250, 256, 0, stream>>>(d_in[0], d_in[1], d_in[2], d_in[3], d_in[4],
                                      d_in[5], d_in[6], d_in[7], d_in[8], d_in[9],
                                      flag, canon);
    hipMemsetAsync(rV, 0, 524288, stream);
    rope_tab_k<<<512, 256, 0, stream>>>(tab);
    dim3 tg(8, 8);
    transpose_k<<<tg, 256, 0, stream>>>(Wqc,  Wt + 0 * 262144);
    transpose_k<<<tg, 256, 0, stream>>>(Wkc,  Wt + 1 * 262144);
    transpose_k<<<tg, 256, 0, stream>>>(Wskc, Wt + 2 * 262144);
    transpose_k<<<tg, 256, 0, stream>>>(Wzc,  Wt + 3 * 262144);
    dim3 gg(8, 256);
    gemm_proj_k<<<gg, 256, 0, stream>>>(Xc, Wt + 0 * 262144, bqc,  q,    0);
    gemm_proj_k<<<gg, 256, 0, stream>>>(Xc, Wt + 1 * 262144, bkc,  k,    0);
    gemm_proj_k<<<gg, 256, 0, stream>>>(Xc, Wt + 2 * 262144, bskc, skip, 0);
    gemm_proj_k<<<gg, 256, 0, stream>>>(Xc, Wt + 3 * 262144, bzc,  z,    1);
    router_scores_k<<<dim3(64, 32), 256, 0, stream>>>(RPc, k, P);
    softmax_rows_k<<<2048, 256, 0, stream>>>(P);
    router_v_k<<<dim3(16, 32), 256, 0, stream>>>(P, Xc, tab, rV);
    final_attn_k<<<dim3(64, 8, 4), 256, 0, stream>>>(q, RPc, rV, tab, skip, z, flag, d_out);
}

// Round 3
// 298.497 us; speedup vs baseline: 1.0176x; 1.0176x over previous
//
#include <hip/hip_runtime.h>

// RouterAttention on gfx950. B=4 L=S=4096 D=512 H=8 E=R=64.
// R3: algebraic restructure — q/k GEMMs eliminated via Wqr = Wq@r^T, Wkr = r@Wk^T
// (bk dropped: constant along softmax axis). One fused 16384x1536x512 MFMA GEMM
// (m97-style global_load_lds staging) + transposed-score router GEMM.

#define DEV __device__ __forceinline__

constexpr int Bn = 4, Ln = 4096, Dn = 512, Hn = 8, En = 64, Rn = 64;
constexpr int Sn = 4096;
constexpr float SCALE = 0.125f;                 // 1/sqrt(E)
constexpr float L2B_OVER_K = 13.287712379549449f / 32.0f; // log2(10000)/32

typedef __bf16 bf16x8 __attribute__((ext_vector_type(8)));
typedef float floatx4 __attribute__((ext_vector_type(4)));

DEV float bf2f(ushort u) { return __uint_as_float(((unsigned)u) << 16); }
DEV ushort f2bf(float f) {
    unsigned u = __float_as_uint(f);
    u += 0x7fffu + ((u >> 16) & 1u);            // RNE
    return (ushort)(u >> 16);
}
DEV bf16x8 ldsfrag(const ushort* p) { return *reinterpret_cast<const bf16x8*>(p); }
#define MFMA(a, b, c) __builtin_amdgcn_mfma_f32_16x16x32_bf16(a, b, c, 0, 0, 0)

DEV void gload16(const ushort* g, ushort* lds) {
    __builtin_amdgcn_global_load_lds(
        (const __attribute__((address_space(1))) unsigned int*)g,
        (__attribute__((address_space(3))) unsigned int*)lds, 16, 0, 0);
}

DEV float wave_max(float v) {
    #pragma unroll
    for (int off = 1; off < 64; off <<= 1) v = fmaxf(v, __shfl_xor(v, off));
    return v;
}
DEV float wave_sum(float v) {
    #pragma unroll
    for (int off = 1; off < 64; off <<= 1) v += __shfl_xor(v, off);
    return v;
}
DEV int wave_sum_i(int v) {
    #pragma unroll
    for (int off = 1; off < 64; off <<= 1) v += __shfl_xor(v, off);
    return v;
}

// ---- dtype sniffer: flag=1 if x looks like f32, 0 if bf16-packed ----
__global__ __launch_bounds__(256) void sniff_k(const uint* __restrict__ x, int* __restrict__ flag) {
    int t = threadIdx.x, cnt = 0;
    #pragma unroll
    for (int i = 0; i < 16; ++i) {
        uint u = x[t * 16 + i];
        uint e = (u >> 7) & 0xFF;
        cnt += (e >= 100 && e <= 140) ? 1 : 0;
    }
    cnt = wave_sum_i(cnt);
    __shared__ int red[4];
    int w = t >> 6, l = t & 63;
    if (l == 0) red[w] = cnt;
    __syncthreads();
    if (t == 0) flag[0] = ((red[0] + red[1] + red[2] + red[3]) < 2048) ? 1 : 0;
}

// ---- canonicalize all 10 inputs into contiguous bf16 region ----
constexpr size_t SEG1 = 8388608, SEG2 = 8650752, SEG3 = 8651264, SEG4 = 8913408,
                 SEG5 = 8913920, SEG6 = 9176064, SEG7 = 9176576, SEG8 = 9438720,
                 SEG9 = 9439232, SEGT = 9472000;
__global__ __launch_bounds__(256)
void canon_k(const void* p0, const void* p1, const void* p2, const void* p3,
             const void* p4, const void* p5, const void* p6, const void* p7,
             const void* p8, const void* p9, const int* __restrict__ flag,
             ushort* __restrict__ dst) {
    const int f = *flag;
    size_t i0 = (size_t)blockIdx.x * 1024 + threadIdx.x;
    #pragma unroll
    for (int r = 0; r < 4; ++r) {
        size_t i = i0 + (size_t)r * 256;
        if (i >= SEGT) return;
        const void* sp; size_t off;
        if      (i < SEG1) { sp = p0; off = i; }
        else if (i < SEG2) { sp = p1; off = i - SEG1; }
        else if (i < SEG3) { sp = p2; off = i - SEG2; }
        else if (i < SEG4) { sp = p3; off = i - SEG3; }
        else if (i < SEG5) { sp = p4; off = i - SEG4; }
        else if (i < SEG6) { sp = p5; off = i - SEG5; }
        else if (i < SEG7) { sp = p6; off = i - SEG6; }
        else if (i < SEG8) { sp = p7; off = i - SEG7; }
        else if (i < SEG9) { sp = p8; off = i - SEG8; }
        else               { sp = p9; off = i - SEG9; }
        dst[i] = f ? f2bf(((const float*)sp)[off]) : ((const ushort*)sp)[off];
    }
}

// ---- rope table: tab[p*32+j] = (cos, sin) of (S-1-p)*theta_j ----
__global__ __launch_bounds__(256) void rope_tab_k(float2* __restrict__ tab) {
    int idx = blockIdx.x * 256 + threadIdx.x;   // 131072 entries
    int p = idx >> 5, j = idx & 31;
    float theta = exp2f(-(float)j * L2B_OVER_K);
    float ang = (float)(Sn - 1 - p) * theta;
    float s, c;
    sincosf(ang, &s, &c);
    tab[idx] = make_float2(c, s);
}

// ---- 512x512 bf16 transpose: Wt[dout][din] = W[din][dout] ----
__global__ __launch_bounds__(256) void transpose_k(const ushort* __restrict__ W, ushort* __restrict__ Wt) {
    __shared__ ushort t[64][65];
    int tid = threadIdx.x;
    int c = tid & 63, r0 = (tid >> 6) * 16;
    int bx = blockIdx.x * 64, by = blockIdx.y * 64;
    #pragma unroll
    for (int i = 0; i < 16; ++i) t[r0 + i][c] = W[(size_t)(by + r0 + i) * Dn + bx + c];
    __syncthreads();
    #pragma unroll
    for (int i = 0; i < 16; ++i) Wt[(size_t)(bx + r0 + i) * Dn + by + c] = t[c][r0 + i];
}

// ---- prep: Wr_t[h*64+ro][d] = SCALE * sum_e W[d][h*64+e] * RP[ro][h*64+e] ----
// z=0: W=Wq -> out Wqr (Wtcat sec2); z=1: W=Wk -> out Wkr
__global__ __launch_bounds__(256)
void prep_wr_k(const ushort* __restrict__ Wq, const ushort* __restrict__ Wk,
               const ushort* __restrict__ RPc, ushort* __restrict__ Wqr,
               ushort* __restrict__ Wkr) {
    __shared__ ushort As[64][72];   // RP slice [ro][e]
    __shared__ ushort Bs[64][72];   // W rows [d][e]
    const int tid = threadIdx.x;
    const int h = blockIdx.y, d0 = blockIdx.x * 64;
    const ushort* W = blockIdx.z ? Wk : Wq;
    ushort* Out = blockIdx.z ? Wkr : Wqr;
    #pragma unroll
    for (int j = 0; j < 2; ++j) {
        int lin = j * 256 + tid, row = lin >> 3, c = (lin & 7) * 8;
        *(uint4*)&As[row][c] = *(const uint4*)&RPc[(size_t)row * Dn + h * En + c];
        *(uint4*)&Bs[row][c] = *(const uint4*)&W[(size_t)(d0 + row) * Dn + h * En + c];
    }
    __syncthreads();
    const int w = tid >> 6, l = tid & 63;
    const int mt = (w >> 1) * 32, nt = (w & 1) * 32, lr = l & 15, lq = l >> 4;
    floatx4 acc[2][2] = {};
    #pragma unroll
    for (int ks = 0; ks < 64; ks += 32) {
        bf16x8 a0 = ldsfrag(&As[mt + lr][ks + lq * 8]);
        bf16x8 a1 = ldsfrag(&As[mt + 16 + lr][ks + lq * 8]);
        bf16x8 b0 = ldsfrag(&Bs[nt + lr][ks + lq * 8]);
        bf16x8 b1 = ldsfrag(&Bs[nt + 16 + lr][ks + lq * 8]);
        acc[0][0] = MFMA(a0, b0, acc[0][0]);
        acc[0][1] = MFMA(a0, b1, acc[0][1]);
        acc[1][0] = MFMA(a1, b0, acc[1][0]);
        acc[1][1] = MFMA(a1, b1, acc[1][1]);
    }
    #pragma unroll
    for (int mi = 0; mi < 2; ++mi)
        #pragma unroll
        for (int ni = 0; ni < 2; ++ni)
            #pragma unroll
            for (int ri = 0; ri < 4; ++ri) {
                int ro = mt + mi * 16 + lq * 4 + ri;
                int d = d0 + nt + ni * 16 + lr;
                Out[(size_t)(h * En + ro) * Dn + d] = f2bf(acc[mi][ni][ri] * SCALE);
            }
}

// ---- bias vector for fused GEMM: [bskip | bz | qb] (qb = SCALE * bq . r) ----
__global__ __launch_bounds__(512)
void prep_bias_k(const ushort* __restrict__ bskc, const ushort* __restrict__ bzc,
                 const ushort* __restrict__ bqc, const ushort* __restrict__ RPc,
                 float* __restrict__ biascat) {
    int i = threadIdx.x;                    // 512 threads
    biascat[i]       = bf2f(bskc[i]);
    biascat[512 + i] = bf2f(bzc[i]);
    int h = i >> 6, ro = i & 63;
    float s = 0.f;
    for (int e = 0; e < 64; ++e)
        s += bf2f(bqc[h * En + e]) * bf2f(RPc[(size_t)ro * Dn + h * En + e]);
    biascat[1024 + i] = s * SCALE;
}

// ---- fused projection GEMM: M=16384 N=1536(skip|z|qs) K=512, 128x128 tiles ----
// LDS chunk-major layout (slot16 = chunk*128 + row) for uniform bank use;
// staged via global_load_lds width 16 (lane-linear constraint satisfied).
__global__ __launch_bounds__(256)
void gemm_fused_k(const ushort* __restrict__ X, const ushort* __restrict__ Wtcat,
                  const float* __restrict__ biascat, ushort* __restrict__ skip,
                  ushort* __restrict__ z, ushort* __restrict__ qs) {
    __shared__ __align__(16) ushort As[8192];   // 128 rows x 64 k, chunk-major
    __shared__ __align__(16) ushort Bs[8192];
    const int tid = threadIdx.x;
    const int w = tid >> 6, l = tid & 63;
    const int n0 = blockIdx.x * 128;
    const int m0 = blockIdx.y * 128;
    const int mt = (w >> 1) * 64, nt = (w & 1) * 64;
    const int lr = l & 15, lq = l >> 4;
    floatx4 acc[4][4] = {};
    for (int kc = 0; kc < Dn; kc += 64) {
        __syncthreads();
        #pragma unroll
        for (int j = 0; j < 4; ++j) {
            int lin = (w * 4 + j) * 64 + l;     // 0..1023 = slot16
            int row = lin & 127, chunk = lin >> 7;
            gload16(&X[(size_t)(m0 + row) * Dn + kc + chunk * 8], &As[(w * 4 + j) * 512]);
            gload16(&Wtcat[(size_t)(n0 + row) * Dn + kc + chunk * 8], &Bs[(w * 4 + j) * 512]);
        }
        __syncthreads();
        #pragma unroll
        for (int ks = 0; ks < 64; ks += 32) {
            bf16x8 a[4], bb[4];
            #pragma unroll
            for (int i = 0; i < 4; ++i)
                a[i] = ldsfrag(&As[(((ks >> 3) + lq) * 128 + mt + 16 * i + lr) * 8]);
            #pragma unroll
            for (int i = 0; i < 4; ++i)
                bb[i] = ldsfrag(&Bs[(((ks >> 3) + lq) * 128 + nt + 16 * i + lr) * 8]);
            #pragma unroll
            for (int mi = 0; mi < 4; ++mi)
                #pragma unroll
                for (int ni = 0; ni < 4; ++ni)
                    acc[mi][ni] = MFMA(a[mi], bb[ni], acc[mi][ni]);
        }
    }
    const int sec = n0 >> 9;                    // 0=skip 1=z 2=qs
    ushort* dst = sec == 0 ? skip : (sec == 1 ? z : qs);
    #pragma unroll
    for (int ni = 0; ni < 4; ++ni) {
        int ng = n0 + nt + ni * 16 + lr;
        float bbv = biascat[ng];
        int nc = ng & 511;
        #pragma unroll
        for (int mi = 0; mi < 4; ++mi)
            #pragma unroll
            for (int ri = 0; ri < 4; ++ri) {
                int row = m0 + mt + mi * 16 + lq * 4 + ri;
                float v = acc[mi][ni][ri] + bbv;
                if (sec == 1) v = v / (1.0f + __expf(-v));
                dst[(size_t)row * Dn + nc] = f2bf(v);
            }
    }
}

// ---- router scores (pre-scaled): P[(bh,r)][s] = Wkr[h*64+r,:] . x[b,s,:] ----
// One x s-tile in LDS serves all 8 heads.
__global__ __launch_bounds__(256)
void rscore_k(const ushort* __restrict__ Wkr, const ushort* __restrict__ X,
              float* __restrict__ P) {
    __shared__ __align__(16) ushort Xs[64][520];  // [s][d] padded
    __shared__ __align__(16) ushort As[64][72];   // Wkr slice [r][64]
    const int tid = threadIdx.x;
    const int b = blockIdx.y, s0 = blockIdx.x * 64;
    #pragma unroll
    for (int i = 0; i < 16; ++i) {
        int lin = i * 256 + tid;                  // uint4 index, 4096 total
        int row = lin >> 6, c = (lin & 63) * 8;
        *(uint4*)&Xs[row][c] = *(const uint4*)&X[(size_t)(b * Ln + s0 + row) * Dn + c];
    }
    const int w = tid >> 6, l = tid & 63;
    const int mt = (w >> 1) * 32, nt = (w & 1) * 32, lr = l & 15, lq = l >> 4;
    for (int h = 0; h < Hn; ++h) {
        floatx4 acc[2][2] = {};
        for (int kc = 0; kc < Dn; kc += 64) {
            __syncthreads();
            #pragma unroll
            for (int j = 0; j < 2; ++j) {
                int lin = j * 256 + tid, row = lin >> 3, c = (lin & 7) * 8;
                *(uint4*)&As[row][c] = *(const uint4*)&Wkr[(size_t)(h * En + row) * Dn + kc + c];
            }
            __syncthreads();
            #pragma unroll
            for (int ks = 0; ks < 64; ks += 32) {
                bf16x8 a0 = ldsfrag(&As[mt + lr][ks + lq * 8]);
                bf16x8 a1 = ldsfrag(&As[mt + 16 + lr][ks + lq * 8]);
                bf16x8 b0 = ldsfrag(&Xs[nt + lr][kc + ks + lq * 8]);
                bf16x8 b1 = ldsfrag(&Xs[nt + 16 + lr][kc + ks + lq * 8]);
                acc[0][0] = MFMA(a0, b0, acc[0][0]);
                acc[0][1] = MFMA(a0, b1, acc[0][1]);
                acc[1][0] = MFMA(a1, b0, acc[1][0]);
                acc[1][1] = MFMA(a1, b1, acc[1][1]);
            }
        }
        #pragma unroll
        for (int mi = 0; mi < 2; ++mi)
            #pragma unroll
            for (int ni = 0; ni < 2; ++ni)
                #pragma unroll
                for (int ri = 0; ri < 4; ++ri) {
                    int r = mt + mi * 16 + lq * 4 + ri;
                    int s = s0 + nt + ni * 16 + lr;
                    P[((size_t)(b * Hn + h) * Rn + r) * Sn + s] = acc[mi][ni][ri];
                }
    }
}

// ---- row softmax over S, in place (input pre-scaled) ----
__global__ __launch_bounds__(256)
void softmax_rows_k(float* __restrict__ P) {
    size_t base = (size_t)blockIdx.x * Sn;
    int tid = threadIdx.x, w = tid >> 6, l = tid & 63;
    float v[16];
    float m = -1e30f;
    #pragma unroll
    for (int i = 0; i < 16; ++i) { v[i] = P[base + i * 256 + tid]; m = fmaxf(m, v[i]); }
    __shared__ float red[4], red2[4];
    m = wave_max(m);
    if (l == 0) red[w] = m;
    __syncthreads();
    m = fmaxf(fmaxf(red[0], red[1]), fmaxf(red[2], red[3]));
    float s = 0.f;
    #pragma unroll
    for (int i = 0; i < 16; ++i) { v[i] = __expf(v[i] - m); s += v[i]; }
    s = wave_sum(s);
    if (l == 0) red2[w] = s;
    __syncthreads();
    float inv = 1.0f / (red2[0] + red2[1] + red2[2] + red2[3]);
    #pragma unroll
    for (int i = 0; i < 16; ++i) P[base + i * 256 + tid] = v[i] * inv;
}

// ---- rV[bh][r][e] += sum_s rope(P)[r][s] * v[s][e] ----
__global__ __launch_bounds__(256)
void router_v_k(const float* __restrict__ P, const ushort* __restrict__ X,
                const float2* __restrict__ tab, float* __restrict__ rV) {
    __shared__ ushort As[64][72];
    __shared__ ushort Bs[64][72];
    const int tid = threadIdx.x;
    const int bh = blockIdx.y, b = bh >> 3, h = bh & 7;
    const int w = tid >> 6, l = tid & 63;
    const int mt = (w >> 1) * 32, nt = (w & 1) * 32, lr = l & 15, lq = l >> 4;
    floatx4 acc[2][2] = {};
    for (int t4 = 0; t4 < 4; ++t4) {
        const int sb = blockIdx.x * 256 + t4 * 64;
        __syncthreads();
        #pragma unroll
        for (int i = 0; i < 8; ++i) {
            int lin = i * 256 + tid;
            int j = lin >> 6, sl = lin & 63;
            int sg2 = sb + sl;
            float pe = P[((size_t)bh * Rn + 2 * j) * Sn + sg2];
            float po = P[((size_t)bh * Rn + 2 * j + 1) * Sn + sg2];
            float2 cs = tab[sg2 * 32 + j];
            As[2 * j][sl]     = f2bf(pe * cs.x - po * cs.y);
            As[2 * j + 1][sl] = f2bf(pe * cs.y + po * cs.x);
        }
        #pragma unroll
        for (int i = 0; i < 16; ++i) {
            int lin = i * 256 + tid;
            int sl = lin >> 6, e = lin & 63;
            Bs[e][sl] = X[(size_t)(b * Ln + sb + sl) * Dn + h * En + e];
        }
        __syncthreads();
        #pragma unroll
        for (int ks = 0; ks < 64; ks += 32) {
            bf16x8 a0 = ldsfrag(&As[mt + lr][ks + lq * 8]);
            bf16x8 a1 = ldsfrag(&As[mt + 16 + lr][ks + lq * 8]);
            bf16x8 b0 = ldsfrag(&Bs[nt + lr][ks + lq * 8]);
            bf16x8 b1 = ldsfrag(&Bs[nt + 16 + lr][ks + lq * 8]);
            acc[0][0] = MFMA(a0, b0, acc[0][0]);
            acc[0][1] = MFMA(a0, b1, acc[0][1]);
            acc[1][0] = MFMA(a1, b0, acc[1][0]);
            acc[1][1] = MFMA(a1, b1, acc[1][1]);
        }
    }
    #pragma unroll
    for (int mi = 0; mi < 2; ++mi)
        #pragma unroll
        for (int ni = 0; ni < 2; ++ni)
            #pragma unroll
            for (int ri = 0; ri < 4; ++ri) {
                int r = mt + mi * 16 + lq * 4 + ri;
                int e = nt + ni * 16 + lr;
                atomicAdd(&rV[((size_t)bh * Rn + r) * En + e], acc[mi][ni][ri]);
            }
}

// ---- fused query path: read qs -> softmax(r) -> rope -> @rV -> (+skip)*z ----
__global__ __launch_bounds__(256)
void final_attn_k(const ushort* __restrict__ QS, const float* __restrict__ rV,
                  const float2* __restrict__ tab, const ushort* __restrict__ Skip,
                  const ushort* __restrict__ Zs, const int* __restrict__ flagp,
                  void* __restrict__ Outv) {
    __shared__ ushort qst[64][72];
    __shared__ ushort Ap[64][72];
    __shared__ ushort BvT[64][72];
    const int f = *flagp;
    const int tid = threadIdx.x;
    const int h = blockIdx.y, b = blockIdx.z, bh = b * Hn + h;
    const int l0 = blockIdx.x * 64;
    const int w = tid >> 6, l = tid & 63;
    const int mt = (w >> 1) * 32, nt = (w & 1) * 32, lr = l & 15, lq = l >> 4;
    #pragma unroll
    for (int j = 0; j < 2; ++j) {
        int lin = j * 256 + tid, row = lin >> 3, c = (lin & 7) * 8;
        *(uint4*)&qst[row][c] = *(const uint4*)&QS[(size_t)(b * Ln + l0 + row) * Dn + h * En + c];
    }
    #pragma unroll
    for (int i = 0; i < 16; ++i) {
        int lin = i * 256 + tid, r = lin >> 6, e = lin & 63;
        BvT[e][r] = f2bf(rV[((size_t)bh * Rn + r) * En + e]);
    }
    __syncthreads();
    #pragma unroll
    for (int ii = 0; ii < 16; ++ii) {           // one token per wave per iter
        int lt = ii * 4 + w;
        float sv = bf2f(qst[lt][l]);            // pre-scaled score, |sv| <~ 8
        float p = __expf(sv);
        float sum = wave_sum(p);
        float A = p / sum;
        float Axp = __shfl_xor(A, 1);
        float2 cs = tab[(l0 + lt) * 32 + (l >> 1)];
        float Ar = (l & 1) ? (Axp * cs.y + A * cs.x) : (A * cs.x - Axp * cs.y);
        Ap[lt][l] = f2bf(Ar);
    }
    __syncthreads();
    floatx4 acc[2][2] = {};
    #pragma unroll
    for (int ks = 0; ks < 64; ks += 32) {
        bf16x8 a0 = ldsfrag(&Ap[mt + lr][ks + lq * 8]);
        bf16x8 a1 = ldsfrag(&Ap[mt + 16 + lr][ks + lq * 8]);
        bf16x8 b0 = ldsfrag(&BvT[nt + lr][ks + lq * 8]);
        bf16x8 b1 = ldsfrag(&BvT[nt + 16 + lr][ks + lq * 8]);
        acc[0][0] = MFMA(a0, b0, acc[0][0]);
        acc[0][1] = MFMA(a0, b1, acc[0][1]);
        acc[1][0] = MFMA(a1, b0, acc[1][0]);
        acc[1][1] = MFMA(a1, b1, acc[1][1]);
    }
    #pragma unroll
    for (int mi = 0; mi < 2; ++mi)
        #pragma unroll
        for (int ni = 0; ni < 2; ++ni)
            #pragma unroll
            for (int ri = 0; ri < 4; ++ri) {
                int row = mt + mi * 16 + lq * 4 + ri;
                int e = nt + ni * 16 + lr;
                size_t idx = (size_t)(b * Ln + l0 + row) * Dn + h * En + e;
                float v = acc[mi][ni][ri];
                float val = (v + bf2f(Skip[idx])) * bf2f(Zs[idx]);
                if (f) ((float*)Outv)[idx] = val;
                else   ((ushort*)Outv)[idx] = f2bf(val);
            }
}

extern "C" void kernel_launch(void* const* d_in, const int* in_sizes, int n_in,
                              void* d_out, int out_size, void* d_ws, size_t ws_size,
                              hipStream_t stream) {
    const size_t OFF_SK    = 0;                  // 16 MiB bf16 [16384][512]
    const size_t OFF_Z     = 16777216;
    const size_t OFF_QS    = 33554432;
    const size_t OFF_P     = 50331648;           // 32 MiB f32
    const size_t OFF_RV    = 83886080;           // 512 KiB f32
    const size_t OFF_TAB   = 84410368;           // 1 MiB
    const size_t OFF_WT    = 85458944;           // Wtcat 1536x512 bf16 = 1.5 MiB
    const size_t OFF_WKR   = 87031808;           // 512x512 bf16
    const size_t OFF_BIAS  = 87556096;           // 1536 f32
    const size_t OFF_CANON = 87562240;           // 18,944,000 B
    const size_t OFF_FLAG  = OFF_CANON + 18944000;
    const size_t NEED      = OFF_FLAG + 16;      // ~101.6 MB
    if (ws_size < NEED) return;

    char* ws = (char*)d_ws;
    ushort* skip  = (ushort*)(ws + OFF_SK);
    ushort* z     = (ushort*)(ws + OFF_Z);
    ushort* qs    = (ushort*)(ws + OFF_QS);
    float*  P     = (float*)(ws + OFF_P);
    float*  rV    = (float*)(ws + OFF_RV);
    float2* tab   = (float2*)(ws + OFF_TAB);
    ushort* Wtcat = (ushort*)(ws + OFF_WT);
    ushort* Wkr   = (ushort*)(ws + OFF_WKR);
    float*  bias  = (float*)(ws + OFF_BIAS);
    ushort* canon = (ushort*)(ws + OFF_CANON);
    int*    flag  = (int*)(ws + OFF_FLAG);

    const ushort* Xc   = canon;
    const ushort* Wqc  = canon + SEG1;
    const ushort* bqc  = canon + SEG2;
    const ushort* Wkc  = canon + SEG3;
    const ushort* Wskc = canon + SEG5;
    const ushort* bskc = canon + SEG6;
    const ushort* Wzc  = canon + SEG7;
    const ushort* bzc  = canon + SEG8;
    const ushort* RPc  = canon + SEG9;

    sniff_k<<<1, 256, 0, stream>>>((const uint*)d_in[0], flag);
    canon_k<<<9250, 256, 0, stream>>>(d_in[0], d_in[1], d_in[2], d_in[3], d_in[4],
                                      d_in[5], d_in[6], d_in[7], d_in[8], d_in[9],
                                      flag, canon);
    hipMemsetAsync(rV, 0, 524288, stream);
    rope_tab_k<<<512, 256, 0, stream>>>(tab);
    dim3 tg(8, 8);
    transpose_k<<<tg, 256, 0, stream>>>(Wskc, Wtcat);            // sec0 = Wskip^T
    transpose_k<<<tg, 256, 0, stream>>>(Wzc,  Wtcat + 262144);   // sec1 = Wz^T
    prep_wr_k<<<dim3(8, 8, 2), 256, 0, stream>>>(Wqc, Wkc, RPc,
                                                 Wtcat + 524288, Wkr); // sec2 = Wqr
    prep_bias_k<<<1, 512, 0, stream>>>(bskc, bzc, bqc, RPc, bias);
    gemm_fused_k<<<dim3(12, 128), 256, 0, stream>>>(Xc, Wtcat, bias, skip, z, qs);
    rscore_k<<<dim3(64, 4), 256, 0, stream>>>(Wkr, Xc, P);
    softmax_rows_k<<<2048, 256, 0, stream>>>(P);
    router_v_k<<<dim3(16, 32), 256, 0, stream>>>(P, Xc, tab, rV);
    final_attn_k<<<dim3(64, 8, 4), 256, 0, stream>>>(qs, rV, tab, skip, z, flag, d_out);
}